// Round 11
// baseline (48.275 us; speedup 1.0000x reference)
//
#include <hip/hip_runtime.h>

#define M_NODES 4096
#define NN_NUM 16
#define G_NUM 4
#define IN_F 32
#define OUT_F 32
#define LOC_F 8
#define LHID 128
#define B_SZ 16
#define NPAIR 65536
#define ROWCAP 64
#define STAGE_D 4   /* async pipeline depth (rows in flight per wave) */

typedef __attribute__((ext_vector_type(8))) short short8;
typedef __attribute__((ext_vector_type(4))) float f32x4;
typedef const unsigned __attribute__((address_space(1))) gbl_u32;
typedef unsigned __attribute__((address_space(3))) lds_u32;

// f32 -> bf16 with round-to-nearest-even
static __device__ __forceinline__ unsigned short f2bf(float f) {
  union { float f; unsigned u; } c; c.f = f;
  const unsigned r = c.u + 0x7FFFu + ((c.u >> 16) & 1u);
  return (unsigned short)(r >> 16);
}
static __device__ __forceinline__ float bfhi2f(unsigned u) {  // high 16 bits
  union { unsigned u; float f; } c; c.u = u & 0xFFFF0000u; return c.f;
}
static __device__ __forceinline__ float bflo2f(unsigned u) {  // low 16 bits
  union { unsigned u; float f; } c; c.u = u << 16; return c.f;
}

// ---------------------------------------------------------------------------
// K0 (prep-lite, identical to round 8): 256 blocks x 256 threads.
// ---------------------------------------------------------------------------
__global__ void __launch_bounds__(256)
prep_kernel(const float* __restrict__ maps,
            const float* __restrict__ W1,
            const float* __restrict__ b1,
            const float* __restrict__ W2,
            const float* __restrict__ Wx,
            uint4* __restrict__ mapsbf4,
            ushort* __restrict__ w1bf,
            float2* __restrict__ b1w2,
            ushort4* __restrict__ wxf4,
            unsigned* __restrict__ rowcount) {
  const int idx = blockIdx.x * 256 + threadIdx.x;   // [0, 65536)

  // maps row -> 8 bf16 packed in one uint4 store
  {
    const float4 a = *reinterpret_cast<const float4*>(maps + (size_t)idx * 8);
    const float4 b = *reinterpret_cast<const float4*>(maps + (size_t)idx * 8 + 4);
    uint4 r;
    r.x = (unsigned)f2bf(a.x) | ((unsigned)f2bf(a.y) << 16);
    r.y = (unsigned)f2bf(a.z) | ((unsigned)f2bf(a.w) << 16);
    r.z = (unsigned)f2bf(b.x) | ((unsigned)f2bf(b.y) << 16);
    r.w = (unsigned)f2bf(b.z) | ((unsigned)f2bf(b.w) << 16);
    mapsbf4[idx] = r;
  }

  if (idx < G_NUM * LHID * LOC_F) w1bf[idx] = f2bf(W1[idx]);   // 4096
  if (idx < G_NUM * LHID)
    b1w2[idx] = make_float2(b1[idx], -2.0f * W2[idx]);         // 512

  // Wx B-fragments: frag f = (g*2+tile)*64 + lane; lane(lo,hi) holds
  // Wx[g][hi*8+q][tile*16+lo] for q=0..7 as bf16x8.
  if (idx < 512) {
    const int l = idx & 63, tile = (idx >> 6) & 1, g = idx >> 7;
    const int lo = l & 15, hi = l >> 4;
    ushort4 r0, r1;
    r0.x = f2bf(Wx[g * 1024 + (hi * 8 + 0) * 32 + tile * 16 + lo]);
    r0.y = f2bf(Wx[g * 1024 + (hi * 8 + 1) * 32 + tile * 16 + lo]);
    r0.z = f2bf(Wx[g * 1024 + (hi * 8 + 2) * 32 + tile * 16 + lo]);
    r0.w = f2bf(Wx[g * 1024 + (hi * 8 + 3) * 32 + tile * 16 + lo]);
    r1.x = f2bf(Wx[g * 1024 + (hi * 8 + 4) * 32 + tile * 16 + lo]);
    r1.y = f2bf(Wx[g * 1024 + (hi * 8 + 5) * 32 + tile * 16 + lo]);
    r1.z = f2bf(Wx[g * 1024 + (hi * 8 + 6) * 32 + tile * 16 + lo]);
    r1.w = f2bf(Wx[g * 1024 + (hi * 8 + 7) * 32 + tile * 16 + lo]);
    wxf4[idx * 2] = r0;
    wxf4[idx * 2 + 1] = r1;
  }

  if (idx < M_NODES) rowcount[idx] = 0;
}

// ---------------------------------------------------------------------------
// K1: MLP via MFMA (identical to round 8 — best known).
// One WAVE per (node, graph): 4096 blocks x 256 thr. Blocks [0,2048) also
// convert x (f32) -> xbf (bf16), one float4 per thread.
// ---------------------------------------------------------------------------
__global__ void __launch_bounds__(256)
mlp_kernel(const float4* __restrict__ x4,
           ushort4* __restrict__ xb4,
           const ushort* __restrict__ mapsbf,
           const ushort* __restrict__ w1bf,
           const float2* __restrict__ b1w2,
           const int* __restrict__ L_idx,
           unsigned* __restrict__ rowcount,
           uint2* __restrict__ csr_jn,
           float4* __restrict__ csr_a) {
  const int t = threadIdx.x;
  const int l = t & 63;
  const int g = t >> 6;              // wave index = graph
  const int node = blockIdx.x;
  const int lo = l & 15;
  const int hi = l >> 4;

  __shared__ float sAttn[G_NUM][16];

  // folded x -> bf16 conversion (blocks [0,2048))
  {
    const int idx = blockIdx.x * 256 + t;
    if (idx < 524288) {
      const float4 v = x4[idx];
      ushort4 o;
      o.x = f2bf(v.x); o.y = f2bf(v.y); o.z = f2bf(v.z); o.w = f2bf(v.w);
      xb4[idx] = o;
    }
  }

  short8 aF = {0, 0, 0, 0, 0, 0, 0, 0};
  if (hi == 0)
    aF = *reinterpret_cast<const short8*>(mapsbf + ((size_t)node * 16 + lo) * 8);

  // weight set for this wave's graph: hoistable, L1-hot
  short8 bF[8];
  float2 bw[8];
#pragma unroll
  for (int tile = 0; tile < 8; ++tile) {
    bF[tile] = *reinterpret_cast<const short8*>(
        w1bf + ((size_t)(g * LHID + tile * 16 + lo)) * 8);
    bw[tile] = b1w2[g * LHID + tile * 16 + lo];
  }

  float cr[4] = {0.f, 0.f, 0.f, 0.f};
#pragma unroll
  for (int tile = 0; tile < 8; ++tile) {
    const float b1v = bw[tile].x;
    const float nw2 = bw[tile].y;   // -2 * W2[h]
    f32x4 c = {b1v, b1v, b1v, b1v};
    c = __builtin_amdgcn_mfma_f32_16x16x32_bf16(aF, bF[tile], c, 0, 0, 0);
#pragma unroll
    for (int r = 0; r < 4; ++r) {
      // W2h*tanh(H) = W2h - 2*W2h/(e^{2H}+1); constants cancel in softmax
      const float e = exp2f(c[r] * 2.885390082f);
      cr[r] = fmaf(nw2, __builtin_amdgcn_rcpf(e + 1.0f), cr[r]);
    }
  }

  // reduce ctx over the 16 lo-lanes (lane bits 0..3)
#pragma unroll
  for (int m = 1; m <= 8; m <<= 1) {
    cr[0] += __shfl_xor(cr[0], m, 64);
    cr[1] += __shfl_xor(cr[1], m, 64);
    cr[2] += __shfl_xor(cr[2], m, 64);
    cr[3] += __shfl_xor(cr[3], m, 64);
  }

  // softmax over the node's 16 pairs (pair = hi*4+r; lane bits 4,5)
  float mx = fmaxf(fmaxf(cr[0], cr[1]), fmaxf(cr[2], cr[3]));
  mx = fmaxf(mx, __shfl_xor(mx, 16, 64));
  mx = fmaxf(mx, __shfl_xor(mx, 32, 64));
  const float e0 = __expf(cr[0] - mx), e1 = __expf(cr[1] - mx);
  const float e2 = __expf(cr[2] - mx), e3 = __expf(cr[3] - mx);
  float s = e0 + e1 + e2 + e3;
  s += __shfl_xor(s, 16, 64);
  s += __shfl_xor(s, 32, 64);
  const float inv = __builtin_amdgcn_rcpf(s);

  if (lo == 0) {
    sAttn[g][hi * 4 + 0] = e0 * inv;
    sAttn[g][hi * 4 + 1] = e1 * inv;
    sAttn[g][hi * 4 + 2] = e2 * inv;
    sAttn[g][hi * 4 + 3] = e3 * inv;
  }
  __syncthreads();

  // CSR fill: wave 0, lanes 0..15, pair p = t
  if (t < 16) {
    const int n = node * 16 + t;
    const unsigned pos = (unsigned)L_idx[n];
    const unsigned i = pos >> 12;
    const unsigned j = pos & (M_NODES - 1);
    const unsigned slot = atomicAdd(&rowcount[i], 1u);
    if (slot < ROWCAP) {
      csr_jn[(size_t)i * ROWCAP + slot] = make_uint2(j, (unsigned)n);
      csr_a[(size_t)i * ROWCAP + slot] =
          make_float4(sAttn[0][t], sAttn[1][t], sAttn[2][t], sAttn[3][t]);
    }
  }
}

// ---------------------------------------------------------------------------
// K2: gather, now ASYNC-PIPELINED. One WAVE per row i; 1024 blocks x 256 thr.
// Per nnz, the wave needs 64 lanes x 16 B from scattered addresses
// (lane(lo,hi) reads xbf byte (lo*4096+j)*64 + hi*16). Instead of a serial
// shfl->load->use chain, rows are staged 4-deep into per-wave-private LDS
// via global_load_lds (global side per-lane scatter, LDS side uniform-base
// + lane*16 = exactly our consume layout). Counted s_waitcnt vmcnt(3) keeps
// 3 rows in flight; all other VMEM is drained before the pipeline so the
// counts track only stage instructions. No barriers (per-wave slots).
// ---------------------------------------------------------------------------
__global__ void __launch_bounds__(256)
gather_kernel(const ushort* __restrict__ xbf,
              const uint2* __restrict__ csr_jn,
              const float4* __restrict__ csr_a,
              const unsigned* __restrict__ rowcount,
              const ushort* __restrict__ wxf,
              const float* __restrict__ bx,
              float* __restrict__ out) {
  const int t = threadIdx.x;
  const int l = t & 63;
  const int w = t >> 6;
  const int i = blockIdx.x * 4 + w;
  const int lo = l & 15;
  const int hi = l >> 4;

  __shared__ uint4 sStage[4][STAGE_D][64];   // 16 KB, per-wave private rows

  const unsigned cnt = min(rowcount[i], (unsigned)ROWCAP);
  const uint2 e = csr_jn[(size_t)i * ROWCAP + l];
  float4 aq = csr_a[(size_t)i * ROWCAP + l];
  const bool valid = (unsigned)l < cnt;
  unsigned myj = valid ? e.x : 0xFFFFFFFFu;   // sentinel: never matches real j
  const unsigned myn = valid ? e.y : 0u;

  bool alive = valid;
  for (unsigned d = 0; d < cnt; ++d) {
    const unsigned jd = __shfl(myj, (int)d);
    const unsigned nd = __shfl(myn, (int)d);
    if (jd == myj && nd > myn) alive = false;   // a later write beats mine
  }
  if (!alive) { aq.x = 0.f; aq.y = 0.f; aq.z = 0.f; aq.w = 0.f; }
  myj &= (M_NODES - 1u);   // pad lanes address a valid row, weight 0

  // pre-packed Wx B-fragments + bias, then DRAIN so vmcnt = stages only
  short8 bF[G_NUM][2];
#pragma unroll
  for (int g = 0; g < G_NUM; ++g)
#pragma unroll
    for (int tile = 0; tile < 2; ++tile)
      bF[g][tile] = *reinterpret_cast<const short8*>(
          wxf + ((size_t)((g * 2 + tile) * 64 + l)) * 8);
  const float bias0 = bx[lo];
  const float bias1 = bx[16 + lo];
  asm volatile("s_waitcnt vmcnt(0)" ::: "memory");

  float acc[G_NUM][8];
#pragma unroll
  for (int g = 0; g < G_NUM; ++g)
#pragma unroll
    for (int q = 0; q < 8; ++q) acc[g][q] = 0.f;

  // per-lane global base: byte (lo*4096)*64 + hi*16; row j adds j*64
  const char* lanebase =
      (const char*)xbf + ((size_t)lo * M_NODES) * 64 + (size_t)hi * 16;
  uint4* mySlots = &sStage[w][0][0];

#define ISSUE_ROW(idx)                                                        \
  do {                                                                        \
    const unsigned js_ = __shfl(myj, (int)(idx));                             \
    __builtin_amdgcn_global_load_lds(                                         \
        (gbl_u32*)(lanebase + (size_t)js_ * 64),                              \
        (lds_u32*)(mySlots + ((idx) & (STAGE_D - 1)) * 64), 16, 0, 0);        \
  } while (0)

  const int icnt = (int)cnt;
  const int pre = icnt < (STAGE_D - 1) ? icnt : (STAGE_D - 1);
  for (int s = 0; s < pre; ++s) ISSUE_ROW(s);

  for (int s = 0; s < icnt; ++s) {
    if (s + STAGE_D - 1 < icnt) {
      ISSUE_ROW(s + STAGE_D - 1);
      asm volatile("s_waitcnt vmcnt(3)" ::: "memory");
    } else {
      asm volatile("s_waitcnt vmcnt(0)" ::: "memory");
    }
    const uint4 xv = mySlots[(s & (STAGE_D - 1)) * 64 + l];
    const float w0 = __shfl(aq.x, s);
    const float w1 = __shfl(aq.y, s);
    const float w2 = __shfl(aq.z, s);
    const float w3 = __shfl(aq.w, s);
    float xf[8];
    xf[0] = bflo2f(xv.x); xf[1] = bfhi2f(xv.x);
    xf[2] = bflo2f(xv.y); xf[3] = bfhi2f(xv.y);
    xf[4] = bflo2f(xv.z); xf[5] = bfhi2f(xv.z);
    xf[6] = bflo2f(xv.w); xf[7] = bfhi2f(xv.w);
#pragma unroll
    for (int q = 0; q < 8; ++q) {
      acc[0][q] = fmaf(w0, xf[q], acc[0][q]);
      acc[1][q] = fmaf(w1, xf[q], acc[1][q]);
      acc[2][q] = fmaf(w2, xf[q], acc[2][q]);
      acc[3][q] = fmaf(w3, xf[q], acc[3][q]);
    }
  }
#undef ISSUE_ROW

  // A-fragments (bf16) and the 8 MFMAs
  f32x4 c0 = {0.f, 0.f, 0.f, 0.f};
  f32x4 c1 = {0.f, 0.f, 0.f, 0.f};
#pragma unroll
  for (int g = 0; g < G_NUM; ++g) {
    short8 aF;
#pragma unroll
    for (int q = 0; q < 8; ++q) aF[q] = (short)f2bf(acc[g][q]);
    c0 = __builtin_amdgcn_mfma_f32_16x16x32_bf16(aF, bF[g][0], c0, 0, 0, 0);
    c1 = __builtin_amdgcn_mfma_f32_16x16x32_bf16(aF, bF[g][1], c1, 0, 0, 0);
  }

#pragma unroll
  for (int r = 0; r < 4; ++r) {
    const int b = hi * 4 + r;
    float* op = out + ((size_t)b * M_NODES + i) * OUT_F;
    op[lo] = c0[r] + bias0;
    op[16 + lo] = c1[r] + bias1;
  }
}

// ---------------------------------------------------------------------------
extern "C" void kernel_launch(void* const* d_in, const int* in_sizes, int n_in,
                              void* d_out, int out_size, void* d_ws, size_t ws_size,
                              hipStream_t stream) {
  const float* x    = (const float*)d_in[0];
  const float* maps = (const float*)d_in[1];
  const int*   L_idx = (const int*)d_in[2];
  const float* W1   = (const float*)d_in[3];
  const float* b1   = (const float*)d_in[4];
  const float* W2   = (const float*)d_in[5];
  // b2 (d_in[6]) cancels in softmax -- unused
  const float* Wx   = (const float*)d_in[7];
  const float* bx   = (const float*)d_in[8];
  float* out = (float*)d_out;

  // workspace layout (16B-aligned blocks)
  char* ws = (char*)d_ws;
  float4*   csr_a    = (float4*)ws;                        //  4 MB @ 0
  uint2*    csr_jn   = (uint2*)(ws + (4u << 20));          //  2 MB @ 4M
  ushort*   xbf      = (ushort*)(ws + (6u << 20));         //  4 MB @ 6M
  unsigned* rowcount = (unsigned*)(ws + (10u << 20));      // 16 KB @ 10M
  ushort*   mapsbf   = (ushort*)(ws + (11u << 20));        //  1 MB @ 11M
  ushort*   w1bf     = (ushort*)(ws + (12u << 20));        //  8 KB @ 12M
  float2*   b1w2     = (float2*)(ws + (12u << 20) + (32u << 10));  // 4 KB
  ushort*   wxf      = (ushort*)(ws + (12u << 20) + (64u << 10));  // 8 KB

  prep_kernel<<<256, 256, 0, stream>>>(
      maps, W1, b1, W2, Wx,
      (uint4*)mapsbf, w1bf, b1w2, (ushort4*)wxf, rowcount);
  mlp_kernel<<<M_NODES, 256, 0, stream>>>(
      (const float4*)x, (ushort4*)xbf, mapsbf, w1bf, b1w2, L_idx,
      rowcount, csr_jn, csr_a);
  gather_kernel<<<M_NODES / 4, 256, 0, stream>>>(
      xbf, csr_jn, csr_a, rowcount, wxf, bx, out);
}

// Round 12
// 47.254 us; speedup vs baseline: 1.0216x; 1.0216x over previous
//
#include <hip/hip_runtime.h>

#define M_NODES 4096
#define NN_NUM 16
#define G_NUM 4
#define IN_F 32
#define OUT_F 32
#define LOC_F 8
#define LHID 128
#define B_SZ 16
#define NPAIR 65536
#define ROWCAP 64

typedef __attribute__((ext_vector_type(8))) short short8;
typedef __attribute__((ext_vector_type(4))) float f32x4;

// f32 -> bf16 with round-to-nearest-even
static __device__ __forceinline__ unsigned short f2bf(float f) {
  union { float f; unsigned u; } c; c.f = f;
  const unsigned r = c.u + 0x7FFFu + ((c.u >> 16) & 1u);
  return (unsigned short)(r >> 16);
}
static __device__ __forceinline__ float bfhi2f(unsigned u) {  // high 16 bits
  union { unsigned u; float f; } c; c.u = u & 0xFFFF0000u; return c.f;
}
static __device__ __forceinline__ float bflo2f(unsigned u) {  // low 16 bits
  union { unsigned u; float f; } c; c.u = u << 16; return c.f;
}

// ---------------------------------------------------------------------------
// K0 (prep-lite, identical to round 8): 256 blocks x 256 threads.
// ---------------------------------------------------------------------------
__global__ void __launch_bounds__(256)
prep_kernel(const float* __restrict__ maps,
            const float* __restrict__ W1,
            const float* __restrict__ b1,
            const float* __restrict__ W2,
            const float* __restrict__ Wx,
            uint4* __restrict__ mapsbf4,
            ushort* __restrict__ w1bf,
            float2* __restrict__ b1w2,
            ushort4* __restrict__ wxf4,
            unsigned* __restrict__ rowcount) {
  const int idx = blockIdx.x * 256 + threadIdx.x;   // [0, 65536)

  // maps row -> 8 bf16 packed in one uint4 store
  {
    const float4 a = *reinterpret_cast<const float4*>(maps + (size_t)idx * 8);
    const float4 b = *reinterpret_cast<const float4*>(maps + (size_t)idx * 8 + 4);
    uint4 r;
    r.x = (unsigned)f2bf(a.x) | ((unsigned)f2bf(a.y) << 16);
    r.y = (unsigned)f2bf(a.z) | ((unsigned)f2bf(a.w) << 16);
    r.z = (unsigned)f2bf(b.x) | ((unsigned)f2bf(b.y) << 16);
    r.w = (unsigned)f2bf(b.z) | ((unsigned)f2bf(b.w) << 16);
    mapsbf4[idx] = r;
  }

  if (idx < G_NUM * LHID * LOC_F) w1bf[idx] = f2bf(W1[idx]);   // 4096
  if (idx < G_NUM * LHID)
    b1w2[idx] = make_float2(b1[idx], -2.0f * W2[idx]);         // 512

  // Wx B-fragments: frag f = (g*2+tile)*64 + lane; lane(lo,hi) holds
  // Wx[g][hi*8+q][tile*16+lo] for q=0..7 as bf16x8.
  if (idx < 512) {
    const int l = idx & 63, tile = (idx >> 6) & 1, g = idx >> 7;
    const int lo = l & 15, hi = l >> 4;
    ushort4 r0, r1;
    r0.x = f2bf(Wx[g * 1024 + (hi * 8 + 0) * 32 + tile * 16 + lo]);
    r0.y = f2bf(Wx[g * 1024 + (hi * 8 + 1) * 32 + tile * 16 + lo]);
    r0.z = f2bf(Wx[g * 1024 + (hi * 8 + 2) * 32 + tile * 16 + lo]);
    r0.w = f2bf(Wx[g * 1024 + (hi * 8 + 3) * 32 + tile * 16 + lo]);
    r1.x = f2bf(Wx[g * 1024 + (hi * 8 + 4) * 32 + tile * 16 + lo]);
    r1.y = f2bf(Wx[g * 1024 + (hi * 8 + 5) * 32 + tile * 16 + lo]);
    r1.z = f2bf(Wx[g * 1024 + (hi * 8 + 6) * 32 + tile * 16 + lo]);
    r1.w = f2bf(Wx[g * 1024 + (hi * 8 + 7) * 32 + tile * 16 + lo]);
    wxf4[idx * 2] = r0;
    wxf4[idx * 2 + 1] = r1;
  }

  if (idx < M_NODES) rowcount[idx] = 0;
}

// ---------------------------------------------------------------------------
// K1: MLP via MFMA. One WAVE per (node, graph): 4096 blocks x 256 thr.
// CHANGE vs r8 (single variable): break the per-tile MFMA->VALU serial
// dependency. Tiles processed in two groups of 4: each group issues its 4
// MFMAs back-to-back (pipelined in the matrix unit, C-frags materialized),
// then one VALU pass over 16 INDEPENDENT exp/rcp chains with 2 partial
// accumulators per r (8 independent FMA chains vs 4 loop-carried depth-8).
// Everything else identical to round 8.
// ---------------------------------------------------------------------------
__global__ void __launch_bounds__(256)
mlp_kernel(const float4* __restrict__ x4,
           ushort4* __restrict__ xb4,
           const ushort* __restrict__ mapsbf,
           const ushort* __restrict__ w1bf,
           const float2* __restrict__ b1w2,
           const int* __restrict__ L_idx,
           unsigned* __restrict__ rowcount,
           uint2* __restrict__ csr_jn,
           float4* __restrict__ csr_a) {
  const int t = threadIdx.x;
  const int l = t & 63;
  const int g = t >> 6;              // wave index = graph
  const int node = blockIdx.x;
  const int lo = l & 15;
  const int hi = l >> 4;

  __shared__ float sAttn[G_NUM][16];

  // folded x -> bf16 conversion (blocks [0,2048))
  {
    const int idx = blockIdx.x * 256 + t;
    if (idx < 524288) {
      const float4 v = x4[idx];
      ushort4 o;
      o.x = f2bf(v.x); o.y = f2bf(v.y); o.z = f2bf(v.z); o.w = f2bf(v.w);
      xb4[idx] = o;
    }
  }

  short8 aF = {0, 0, 0, 0, 0, 0, 0, 0};
  if (hi == 0)
    aF = *reinterpret_cast<const short8*>(mapsbf + ((size_t)node * 16 + lo) * 8);

  // weight set for this wave's graph: hoistable, L1-hot
  short8 bF[8];
  float2 bw[8];
#pragma unroll
  for (int tile = 0; tile < 8; ++tile) {
    bF[tile] = *reinterpret_cast<const short8*>(
        w1bf + ((size_t)(g * LHID + tile * 16 + lo)) * 8);
    bw[tile] = b1w2[g * LHID + tile * 16 + lo];
  }

  float pa[4] = {0.f, 0.f, 0.f, 0.f};   // partials (even tiles of group)
  float pb[4] = {0.f, 0.f, 0.f, 0.f};   // partials (odd tiles of group)
#pragma unroll
  for (int half = 0; half < 2; ++half) {
    // phase 1: 4 back-to-back MFMAs, C-frags materialized
    f32x4 c0v, c1v, c2v, c3v;
    {
      const float b10 = bw[half * 4 + 0].x;
      const float b11 = bw[half * 4 + 1].x;
      const float b12 = bw[half * 4 + 2].x;
      const float b13 = bw[half * 4 + 3].x;
      f32x4 i0 = {b10, b10, b10, b10};
      f32x4 i1 = {b11, b11, b11, b11};
      f32x4 i2 = {b12, b12, b12, b12};
      f32x4 i3 = {b13, b13, b13, b13};
      c0v = __builtin_amdgcn_mfma_f32_16x16x32_bf16(aF, bF[half * 4 + 0], i0, 0, 0, 0);
      c1v = __builtin_amdgcn_mfma_f32_16x16x32_bf16(aF, bF[half * 4 + 1], i1, 0, 0, 0);
      c2v = __builtin_amdgcn_mfma_f32_16x16x32_bf16(aF, bF[half * 4 + 2], i2, 0, 0, 0);
      c3v = __builtin_amdgcn_mfma_f32_16x16x32_bf16(aF, bF[half * 4 + 3], i3, 0, 0, 0);
    }
    // phase 2: 16 independent exp/rcp chains, 8 independent accumulators
    const float w20 = bw[half * 4 + 0].y;
    const float w21 = bw[half * 4 + 1].y;
    const float w22 = bw[half * 4 + 2].y;
    const float w23 = bw[half * 4 + 3].y;
#pragma unroll
    for (int r = 0; r < 4; ++r) {
      // W2h*tanh(H) = W2h - 2*W2h/(e^{2H}+1); constants cancel in softmax
      const float ea = exp2f(c0v[r] * 2.885390082f);
      const float eb = exp2f(c1v[r] * 2.885390082f);
      const float ec = exp2f(c2v[r] * 2.885390082f);
      const float ed = exp2f(c3v[r] * 2.885390082f);
      pa[r] = fmaf(w20, __builtin_amdgcn_rcpf(ea + 1.0f), pa[r]);
      pb[r] = fmaf(w21, __builtin_amdgcn_rcpf(eb + 1.0f), pb[r]);
      pa[r] = fmaf(w22, __builtin_amdgcn_rcpf(ec + 1.0f), pa[r]);
      pb[r] = fmaf(w23, __builtin_amdgcn_rcpf(ed + 1.0f), pb[r]);
    }
  }
  float cr[4];
#pragma unroll
  for (int r = 0; r < 4; ++r) cr[r] = pa[r] + pb[r];

  // reduce ctx over the 16 lo-lanes (lane bits 0..3)
#pragma unroll
  for (int m = 1; m <= 8; m <<= 1) {
    cr[0] += __shfl_xor(cr[0], m, 64);
    cr[1] += __shfl_xor(cr[1], m, 64);
    cr[2] += __shfl_xor(cr[2], m, 64);
    cr[3] += __shfl_xor(cr[3], m, 64);
  }

  // softmax over the node's 16 pairs (pair = hi*4+r; lane bits 4,5)
  float mx = fmaxf(fmaxf(cr[0], cr[1]), fmaxf(cr[2], cr[3]));
  mx = fmaxf(mx, __shfl_xor(mx, 16, 64));
  mx = fmaxf(mx, __shfl_xor(mx, 32, 64));
  const float e0 = __expf(cr[0] - mx), e1 = __expf(cr[1] - mx);
  const float e2 = __expf(cr[2] - mx), e3 = __expf(cr[3] - mx);
  float s = e0 + e1 + e2 + e3;
  s += __shfl_xor(s, 16, 64);
  s += __shfl_xor(s, 32, 64);
  const float inv = __builtin_amdgcn_rcpf(s);

  if (lo == 0) {
    sAttn[g][hi * 4 + 0] = e0 * inv;
    sAttn[g][hi * 4 + 1] = e1 * inv;
    sAttn[g][hi * 4 + 2] = e2 * inv;
    sAttn[g][hi * 4 + 3] = e3 * inv;
  }
  __syncthreads();

  // CSR fill: wave 0, lanes 0..15, pair p = t
  if (t < 16) {
    const int n = node * 16 + t;
    const unsigned pos = (unsigned)L_idx[n];
    const unsigned i = pos >> 12;
    const unsigned j = pos & (M_NODES - 1);
    const unsigned slot = atomicAdd(&rowcount[i], 1u);
    if (slot < ROWCAP) {
      csr_jn[(size_t)i * ROWCAP + slot] = make_uint2(j, (unsigned)n);
      csr_a[(size_t)i * ROWCAP + slot] =
          make_float4(sAttn[0][t], sAttn[1][t], sAttn[2][t], sAttn[3][t]);
    }
  }
}

// ---------------------------------------------------------------------------
// K2: one WAVE per output row i (identical to round 8 — best known).
// ---------------------------------------------------------------------------
__global__ void __launch_bounds__(256)
gather_kernel(const ushort* __restrict__ xbf,
              const uint2* __restrict__ csr_jn,
              const float4* __restrict__ csr_a,
              const unsigned* __restrict__ rowcount,
              const ushort* __restrict__ wxf,
              const float* __restrict__ bx,
              float* __restrict__ out) {
  const int t = threadIdx.x;
  const int l = t & 63;
  const int i = blockIdx.x * 4 + (t >> 6);
  const int lo = l & 15;
  const int hi = l >> 4;

  // pre-packed B-fragments: 8 coalesced b128 loads
  short8 bF[G_NUM][2];
#pragma unroll
  for (int g = 0; g < G_NUM; ++g)
#pragma unroll
    for (int tile = 0; tile < 2; ++tile)
      bF[g][tile] = *reinterpret_cast<const short8*>(
          wxf + ((size_t)((g * 2 + tile) * 64 + l)) * 8);

  const unsigned cnt = min(rowcount[i], (unsigned)ROWCAP);
  const uint2 e = csr_jn[(size_t)i * ROWCAP + l];
  float4 aq = csr_a[(size_t)i * ROWCAP + l];
  const bool valid = (unsigned)l < cnt;
  unsigned myj = valid ? e.x : 0xFFFFFFFFu;   // sentinel: never matches real j
  const unsigned myn = valid ? e.y : 0u;

  bool alive = valid;
  for (unsigned d = 0; d < cnt; ++d) {
    const unsigned jd = __shfl(myj, (int)d);
    const unsigned nd = __shfl(myn, (int)d);
    if (jd == myj && nd > myn) alive = false;   // a later write beats mine
  }
  if (!alive) { aq.x = 0.f; aq.y = 0.f; aq.z = 0.f; aq.w = 0.f; }
  myj &= (M_NODES - 1u);

  float acc[G_NUM][8];
#pragma unroll
  for (int g = 0; g < G_NUM; ++g)
#pragma unroll
    for (int q = 0; q < 8; ++q) acc[g][q] = 0.f;

  // xbf row segment for this lane: bytes (lo*4096 + j)*64 + hi*16
  const uint4* xrow = reinterpret_cast<const uint4*>(xbf) + hi;
  const size_t browbase = (size_t)lo * M_NODES * 4;

  for (unsigned s = 0; s < cnt; ++s) {
    const unsigned js = __shfl(myj, (int)s);
    const float w0 = __shfl(aq.x, (int)s);
    const float w1 = __shfl(aq.y, (int)s);
    const float w2 = __shfl(aq.z, (int)s);
    const float w3 = __shfl(aq.w, (int)s);
    const uint4 xv = xrow[browbase + (size_t)js * 4];
    float xf[8];
    xf[0] = bflo2f(xv.x); xf[1] = bfhi2f(xv.x);
    xf[2] = bflo2f(xv.y); xf[3] = bfhi2f(xv.y);
    xf[4] = bflo2f(xv.z); xf[5] = bfhi2f(xv.z);
    xf[6] = bflo2f(xv.w); xf[7] = bfhi2f(xv.w);
#pragma unroll
    for (int q = 0; q < 8; ++q) {
      acc[0][q] = fmaf(w0, xf[q], acc[0][q]);
      acc[1][q] = fmaf(w1, xf[q], acc[1][q]);
      acc[2][q] = fmaf(w2, xf[q], acc[2][q]);
      acc[3][q] = fmaf(w3, xf[q], acc[3][q]);
    }
  }

  // A-fragments (bf16) and the 8 MFMAs
  f32x4 c0 = {0.f, 0.f, 0.f, 0.f};
  f32x4 c1 = {0.f, 0.f, 0.f, 0.f};
#pragma unroll
  for (int g = 0; g < G_NUM; ++g) {
    short8 aF;
#pragma unroll
    for (int q = 0; q < 8; ++q) aF[q] = (short)f2bf(acc[g][q]);
    c0 = __builtin_amdgcn_mfma_f32_16x16x32_bf16(aF, bF[g][0], c0, 0, 0, 0);
    c1 = __builtin_amdgcn_mfma_f32_16x16x32_bf16(aF, bF[g][1], c1, 0, 0, 0);
  }

  const float bias0 = bx[lo];
  const float bias1 = bx[16 + lo];
#pragma unroll
  for (int r = 0; r < 4; ++r) {
    const int b = hi * 4 + r;
    float* op = out + ((size_t)b * M_NODES + i) * OUT_F;
    op[lo] = c0[r] + bias0;
    op[16 + lo] = c1[r] + bias1;
  }
}

// ---------------------------------------------------------------------------
extern "C" void kernel_launch(void* const* d_in, const int* in_sizes, int n_in,
                              void* d_out, int out_size, void* d_ws, size_t ws_size,
                              hipStream_t stream) {
  const float* x    = (const float*)d_in[0];
  const float* maps = (const float*)d_in[1];
  const int*   L_idx = (const int*)d_in[2];
  const float* W1   = (const float*)d_in[3];
  const float* b1   = (const float*)d_in[4];
  const float* W2   = (const float*)d_in[5];
  // b2 (d_in[6]) cancels in softmax -- unused
  const float* Wx   = (const float*)d_in[7];
  const float* bx   = (const float*)d_in[8];
  float* out = (float*)d_out;

  // workspace layout (16B-aligned blocks)
  char* ws = (char*)d_ws;
  float4*   csr_a    = (float4*)ws;                        //  4 MB @ 0
  uint2*    csr_jn   = (uint2*)(ws + (4u << 20));          //  2 MB @ 4M
  ushort*   xbf      = (ushort*)(ws + (6u << 20));         //  4 MB @ 6M
  unsigned* rowcount = (unsigned*)(ws + (10u << 20));      // 16 KB @ 10M
  ushort*   mapsbf   = (ushort*)(ws + (11u << 20));        //  1 MB @ 11M
  ushort*   w1bf     = (ushort*)(ws + (12u << 20));        //  8 KB @ 12M
  float2*   b1w2     = (float2*)(ws + (12u << 20) + (32u << 10));  // 4 KB
  ushort*   wxf      = (ushort*)(ws + (12u << 20) + (64u << 10));  // 8 KB

  prep_kernel<<<256, 256, 0, stream>>>(
      maps, W1, b1, W2, Wx,
      (uint4*)mapsbf, w1bf, b1w2, (ushort4*)wxf, rowcount);
  mlp_kernel<<<M_NODES, 256, 0, stream>>>(
      (const float4*)x, (ushort4*)xbf, mapsbf, w1bf, b1w2, L_idx,
      rowcount, csr_jn, csr_a);
  gather_kernel<<<M_NODES / 4, 256, 0, stream>>>(
      xbf, csr_jn, csr_a, rowcount, wxf, bx, out);
}